// Round 12
// baseline (138.099 us; speedup 1.0000x reference)
//
#include <hip/hip_runtime.h>
#include <math.h>

#pragma float_control(precise, on)

#define EPSF 1e-8f

// R34: CORRECTNESS RESTORE. R33 moved MT math into mt_test, which sat
// OUTSIDE the kernels' lexical `#pragma clang fp contract(off)` scope =>
// FMA contraction changed u/v/t bits => absmax 1.5e-5 -> 0.00195 (a grazing
// hit flipped off the R21-certified signature). Fix: contract(off) INSIDE
// mt_test. Structure otherwise identical to R33 (two-dispatch chassis,
// unroll x2 + split accumulators — bit-safe exact-min partition).

// ---------------------------------------------------------------------------
// KNN (K=8) + coarse normal + triangle SoA prep. UNCHANGED from R30/R32/R33.
// ---------------------------------------------------------------------------
__global__ void __launch_bounds__(256) knn_prep_kernel(
    const float* __restrict__ x, const float* __restrict__ verts,
    const float* __restrict__ vnorm, const int* __restrict__ faces,
    float* __restrict__ tri, float* __restrict__ ncw,
    float* __restrict__ v1w, float* __restrict__ dfbw,
    int N, int V, int F) {
#pragma clang fp contract(off)
    int p = blockIdx.x;
    int tid = threadIdx.x;
    int wave = tid >> 6;
    int lane = tid & 63;
    if (p >= N) return;

    int gt = p * 256 + tid;
    if (gt < F) {
        int f0 = faces[gt * 3 + 0];
        int f1 = faces[gt * 3 + 1];
        int f2 = faces[gt * 3 + 2];
        float t0x = verts[f0 * 3 + 0], t0y = verts[f0 * 3 + 1], t0z = verts[f0 * 3 + 2];
        float ax = verts[f1 * 3 + 0], ay = verts[f1 * 3 + 1], az = verts[f1 * 3 + 2];
        float bx = verts[f2 * 3 + 0], by = verts[f2 * 3 + 1], bz = verts[f2 * 3 + 2];
        float4* t4 = (float4*)(tri + (size_t)gt * 12);
        t4[0] = make_float4(t0x, t0y, t0z, ax - t0x);
        t4[1] = make_float4(ay - t0y, az - t0z, bx - t0x, by - t0y);
        t4[2] = make_float4(bz - t0z, 0.f, 0.f, 0.f);
    }

    float xx = x[p * 3 + 0];
    float xy = x[p * 3 + 1];
    float xz = x[p * 3 + 2];

    unsigned long long ka[8], kb[8];
#pragma unroll
    for (int i = 0; i < 8; ++i) { ka[i] = ~0ULL; kb[i] = ~0ULL; }

    for (int va = tid; va < V; va += 512) {
        int vb = va + 256;
        bool hasB = vb < V;

        float avx = verts[va * 3 + 0];
        float avy = verts[va * 3 + 1];
        float avz = verts[va * 3 + 2];
        float bvx = 0.f, bvy = 0.f, bvz = 0.f;
        if (hasB) {
            bvx = verts[vb * 3 + 0];
            bvy = verts[vb * 3 + 1];
            bvz = verts[vb * 3 + 2];
        }

        float dxa = xx - avx, dya = xy - avy, dza = xz - avz;
        float d2a = ((dxa * dxa) + (dya * dya)) + (dza * dza);
        unsigned long long kA =
            (((unsigned long long)__float_as_uint(d2a)) << 32) | (unsigned int)va;
        if (kA < ka[7]) {
            ka[7] = kA;
#pragma unroll
            for (int j = 7; j > 0; --j) {
                if (ka[j] < ka[j - 1]) {
                    unsigned long long t = ka[j];
                    ka[j] = ka[j - 1];
                    ka[j - 1] = t;
                }
            }
        }

        if (hasB) {
            float dxb = xx - bvx, dyb = xy - bvy, dzb = xz - bvz;
            float d2b = ((dxb * dxb) + (dyb * dyb)) + (dzb * dzb);
            unsigned long long kB =
                (((unsigned long long)__float_as_uint(d2b)) << 32) | (unsigned int)vb;
            if (kB < kb[7]) {
                kb[7] = kB;
#pragma unroll
                for (int j = 7; j > 0; --j) {
                    if (kb[j] < kb[j - 1]) {
                        unsigned long long t = kb[j];
                        kb[j] = kb[j - 1];
                        kb[j - 1] = t;
                    }
                }
            }
        }
    }

    unsigned long long wsel[8];
#pragma unroll
    for (int j = 0; j < 8; ++j) {
        unsigned long long c = (ka[0] < kb[0]) ? ka[0] : kb[0];
        unsigned long long m = c;
#pragma unroll
        for (int s = 1; s < 64; s <<= 1) {
            unsigned long long o = __shfl_xor(m, s, 64);
            if (o < m) m = o;
        }
        if (c == m) {
            if (ka[0] == m) {
#pragma unroll
                for (int t = 0; t < 7; ++t) ka[t] = ka[t + 1];
                ka[7] = ~0ULL;
            } else {
#pragma unroll
                for (int t = 0; t < 7; ++t) kb[t] = kb[t + 1];
                kb[7] = ~0ULL;
            }
        }
        wsel[j] = m;
    }

    __shared__ unsigned long long cand[32];
    if (lane == 0) {
#pragma unroll
        for (int j = 0; j < 8; ++j) cand[wave * 8 + j] = wsel[j];
    }
    __syncthreads();
    if (wave != 0) return;

    unsigned long long c0 = (lane < 32) ? cand[lane] : ~0ULL;
    unsigned long long sel[8];
#pragma unroll
    for (int j = 0; j < 8; ++j) {
        unsigned long long m = c0;
#pragma unroll
        for (int s = 1; s < 64; s <<= 1) {
            unsigned long long o = __shfl_xor(m, s, 64);
            if (o < m) m = o;
        }
        if (c0 == m) c0 = ~0ULL;
        sel[j] = m;
    }

    if (lane != 0) return;

    float invk[8];
    float nsx = 0.f, nsy = 0.f, nsz = 0.f;
#pragma unroll
    for (int j = 0; j < 8; ++j) {
        int id = (int)(sel[j] & 0xffffffffu);
        float d2 = __uint_as_float((unsigned int)(sel[j] >> 32));
        float inv = 1.0f / fmaxf(d2, EPSF);
        invk[j] = inv;
        nsx = nsx + vnorm[id * 3 + 0] * inv;
        nsy = nsy + vnorm[id * 3 + 1] * inv;
        nsz = nsz + vnorm[id * 3 + 2] * inv;
    }
    float Wsum = ((invk[0] + invk[1]) + (invk[2] + invk[3])) +
                 ((invk[4] + invk[5]) + (invk[6] + invk[7]));

    int id0 = (int)(sel[0] & 0xffffffffu);
    float v1x = verts[id0 * 3 + 0];
    float v1y = verts[id0 * 3 + 1];
    float v1z = verts[id0 * 3 + 2];

    float dxv = xx - v1x, dyv = xy - v1y, dzv = xz - v1z;
    float d2v1 = fmaxf(((dxv * dxv) + (dyv * dyv)) + (dzv * dzv), EPSF);
    float den = 0.01f * d2v1;
    float tdx = dxv / den, tdy = dyv / den, tdz = dzv / den;

    float W = Wsum + 100.0f;
    float ntx = (nsx + tdx) / W;
    float nty = (nsy + tdy) / W;
    float ntz = (nsz + tdz) / W;
    float nrm = sqrtf(((ntx * ntx) + (nty * nty)) + (ntz * ntz)) + 1e-8f;
    float ncx = ntx / nrm, ncy = nty / nrm, ncz = ntz / nrm;

    float fx = v1x - xx, fy = v1y - xy, fz = v1z - xz;
    float fn = sqrtf(((fx * fx) + (fy * fy)) + (fz * fz)) + 1e-8f;
    fx = fx / fn; fy = fy / fn; fz = fz / fn;

    ncw[p * 3 + 0] = ncx; ncw[p * 3 + 1] = ncy; ncw[p * 3 + 2] = ncz;
    v1w[p * 3 + 0] = v1x; v1w[p * 3 + 1] = v1y; v1w[p * 3 + 2] = v1z;
    dfbw[p * 3 + 0] = fx; dfbw[p * 3 + 1] = fy; dfbw[p * 3 + 2] = fz;
}

// ---------------------------------------------------------------------------
// One MT test, R30-verbatim op order, CONTRACT OFF INSIDE (the R33 bug was
// this pragma missing here — lexical scope, not inline-site).
// ---------------------------------------------------------------------------
__device__ __forceinline__ float mt_test(
    float ox, float oy, float oz, float dx, float dy, float dz,
    const float4 A, const float4 B, const float4 C, float tb) {
#pragma clang fp contract(off)
    const float M = 1e-5f;  // graze margin (R21-certified)
    float e1x = A.w, e1y = B.x, e1z = B.y;
    float e2x = B.z, e2y = B.w, e2z = C.x;
    float tvx = ox - A.x;
    float tvy = oy - A.y;
    float tvz = oz - A.z;
    float qx = (tvy * e1z) - (tvz * e1y);
    float qy = (tvz * e1x) - (tvx * e1z);
    float qz = (tvx * e1y) - (tvy * e1x);
    float tq = ((e2x * qx) + (e2y * qy)) + (e2z * qz);
    float px = (dy * e2z) - (dz * e2y);
    float py = (dz * e2x) - (dx * e2z);
    float pz = (dx * e2y) - (dy * e2x);
    float det = ((e1x * px) + (e1y * py)) + (e1z * pz);
    bool ok = fabsf(det) > EPSF;
    float inv = ok ? (1.0f / det) : 0.0f;
    float u = (((tvx * px) + (tvy * py)) + (tvz * pz)) * inv;
    float v = (((dx * qx) + (dy * qy)) + (dz * qz)) * inv;
    float t = tq * inv;
    bool valid = ok && (u >= -M) && (v >= -M) && ((u + v) <= 1.0f + M) && (t > EPSF);
    return (valid && t < tb) ? t : tb;
}

// ---------------------------------------------------------------------------
// ray + reduce + finalize: block = point. Pass-A (-nc) unrolled x2 with
// split accumulators; pass-B (dfb) conditional (block-uniform), same unroll.
// ---------------------------------------------------------------------------
__global__ void __launch_bounds__(256) ray_fin_kernel(
    const float* __restrict__ x, const float* __restrict__ tri,
    const float* __restrict__ ncw, const float* __restrict__ v1w,
    const float* __restrict__ dfbw, float* __restrict__ out, int N, int F) {
#pragma clang fp contract(off)
    __shared__ unsigned int red[4];
    __shared__ unsigned int u1s, u2s, hflag;
    int p = blockIdx.x;
    int tid = threadIdx.x;
    int wave = tid >> 6;
    int lane = tid & 63;
    if (p >= N) return;

    float xx = x[p * 3 + 0];
    float xy = x[p * 3 + 1];
    float xz = x[p * 3 + 2];
    float ncx = ncw[p * 3 + 0], ncy = ncw[p * 3 + 1], ncz = ncw[p * 3 + 2];
    float dbx = dfbw[p * 3 + 0], dby = dfbw[p * 3 + 1], dbz = dfbw[p * 3 + 2];
    float dax = -ncx, day = -ncy, daz = -ncz;

    const float INF = __uint_as_float(0x7f800000u);

    // -------- pass A: ray-a (-nc), unrolled x2, split accumulators --------
    float tba0 = INF, tba1 = INF;
    int fi = tid;
    for (; fi + 256 < F; fi += 512) {
        const float4 A0 = *(const float4*)(tri + (size_t)fi * 12);
        const float4 B0 = *(const float4*)(tri + (size_t)fi * 12 + 4);
        const float4 C0 = *(const float4*)(tri + (size_t)fi * 12 + 8);
        const float4 A1 = *(const float4*)(tri + (size_t)(fi + 256) * 12);
        const float4 B1 = *(const float4*)(tri + (size_t)(fi + 256) * 12 + 4);
        const float4 C1 = *(const float4*)(tri + (size_t)(fi + 256) * 12 + 8);
        tba0 = mt_test(xx, xy, xz, dax, day, daz, A0, B0, C0, tba0);
        tba1 = mt_test(xx, xy, xz, dax, day, daz, A1, B1, C1, tba1);
    }
    for (; fi < F; fi += 256) {
        const float4 A0 = *(const float4*)(tri + (size_t)fi * 12);
        const float4 B0 = *(const float4*)(tri + (size_t)fi * 12 + 4);
        const float4 C0 = *(const float4*)(tri + (size_t)fi * 12 + 8);
        tba0 = mt_test(xx, xy, xz, dax, day, daz, A0, B0, C0, tba0);
    }

    {
        unsigned int ma = min(__float_as_uint(tba0), __float_as_uint(tba1));
#pragma unroll
        for (int s = 1; s < 64; s <<= 1) {
            unsigned int oa = __shfl_xor(ma, s, 64);
            if (oa < ma) ma = oa;
        }
        if (lane == 0) red[wave] = ma;
    }
    __syncthreads();
    if (tid == 0) {
        unsigned int u1 = min(min(red[0], red[1]), min(red[2], red[3]));
        u1s = u1;
        hflag = (u1 < 0x7f800000u) ? 1u : 0u;
    }
    __syncthreads();

    // -------- pass B: ray-b (dfb), only if ray-a missed (block-uniform) ---
    if (hflag == 0u) {
        float tbb0 = INF, tbb1 = INF;
        int gi = tid;
        for (; gi + 256 < F; gi += 512) {
            const float4 A0 = *(const float4*)(tri + (size_t)gi * 12);
            const float4 B0 = *(const float4*)(tri + (size_t)gi * 12 + 4);
            const float4 C0 = *(const float4*)(tri + (size_t)gi * 12 + 8);
            const float4 A1 = *(const float4*)(tri + (size_t)(gi + 256) * 12);
            const float4 B1 = *(const float4*)(tri + (size_t)(gi + 256) * 12 + 4);
            const float4 C1 = *(const float4*)(tri + (size_t)(gi + 256) * 12 + 8);
            tbb0 = mt_test(xx, xy, xz, dbx, dby, dbz, A0, B0, C0, tbb0);
            tbb1 = mt_test(xx, xy, xz, dbx, dby, dbz, A1, B1, C1, tbb1);
        }
        for (; gi < F; gi += 256) {
            const float4 A0 = *(const float4*)(tri + (size_t)gi * 12);
            const float4 B0 = *(const float4*)(tri + (size_t)gi * 12 + 4);
            const float4 C0 = *(const float4*)(tri + (size_t)gi * 12 + 8);
            tbb0 = mt_test(xx, xy, xz, dbx, dby, dbz, A0, B0, C0, tbb0);
        }
        unsigned int mb = min(__float_as_uint(tbb0), __float_as_uint(tbb1));
#pragma unroll
        for (int s = 1; s < 64; s <<= 1) {
            unsigned int ob = __shfl_xor(mb, s, 64);
            if (ob < mb) mb = ob;
        }
        if (lane == 0) red[wave] = mb;
        __syncthreads();
        if (tid == 0)
            u2s = min(min(red[0], red[1]), min(red[2], red[3]));
    }

    // -------- finalize (verbatim), thread 0 --------
    if (tid != 0) return;
    float t1 = __uint_as_float(u1s);
    bool h1 = t1 < INF;
    float t2 = h1 ? INF : __uint_as_float(u2s);
    bool h2 = t2 < INF;

    float xcx, xcy, xcz;
    if (h1) {
        xcx = xx + ((-ncx) * t1);
        xcy = xy + ((-ncy) * t1);
        xcz = xz + ((-ncz) * t1);
    } else if (h2) {
        xcx = xx + (dbx * t2);
        xcy = xy + (dby * t2);
        xcz = xz + (dbz * t2);
    } else {
        xcx = v1w[p * 3 + 0]; xcy = v1w[p * 3 + 1]; xcz = v1w[p * 3 + 2];
    }
    float s = (((xx - xcx) * ncx) + ((xy - xcy) * ncy)) + ((xz - xcz) * ncz);

    out[p * 3 + 0] = xcx;
    out[p * 3 + 1] = xcy;
    out[p * 3 + 2] = xcz;
    out[3 * N + p] = s;
    out[4 * N + p * 3 + 0] = ncx;
    out[4 * N + p * 3 + 1] = ncy;
    out[4 * N + p * 3 + 2] = ncz;
}

// ---------------------------------------------------------------------------
extern "C" void kernel_launch(void* const* d_in, const int* in_sizes, int n_in,
                              void* d_out, int out_size, void* d_ws, size_t ws_size,
                              hipStream_t stream) {
    const float* x     = (const float*)d_in[0];
    const float* verts = (const float*)d_in[1];
    const float* vnorm = (const float*)d_in[2];
    const int*   faces = (const int*)d_in[3];
    int N = in_sizes[0] / 3;
    int V = in_sizes[1] / 3;
    int F = in_sizes[3] / 3;

    float* tri  = (float*)d_ws;          // F*12 floats (16B-aligned AoS)
    float* ncw  = tri + (size_t)F * 12;  // 3*N
    float* v1w  = ncw + 3 * N;           // 3*N
    float* dfbw = v1w + 3 * N;           // 3*N

    hipLaunchKernelGGL(knn_prep_kernel, dim3(N), dim3(256), 0, stream,
                       x, verts, vnorm, faces, tri, ncw, v1w, dfbw, N, V, F);
    hipLaunchKernelGGL(ray_fin_kernel, dim3(N), dim3(256), 0, stream,
                       x, tri, ncw, v1w, dfbw, (float*)d_out, N, F);
}

// Round 13
// 133.381 us; speedup vs baseline: 1.0354x; 1.0354x over previous
//
#include <hip/hip_runtime.h>
#include <math.h>

#pragma float_control(precise, on)

#define EPSF 1e-8f

// R35: L2-traffic halving WITH full occupancy.
// R32 (2 pts/block, 256 thr, 1024 blocks) halved tri L2 traffic but dropped
// occupancy to 23% => neutral. R35: 2 pts/block with 512 THREADS — grid
// 1024 x 512 = 4 blocks/CU x 8 waves = 2048 thr/CU (full wave capacity).
// Each triangle loaded once, tested vs both points (2 independent MT chains
// = the ILP the x2 unroll provided; unroll dropped). mt_test is the
// R34-certified contract-off version, verbatim => bit-identical outputs.
// Pass-B (dfb) per-point-guarded (block-uniform); finalize verbatim.

// ---------------------------------------------------------------------------
// KNN (K=8) + coarse normal + triangle SoA prep. UNCHANGED from R30..R34.
// ---------------------------------------------------------------------------
__global__ void __launch_bounds__(256) knn_prep_kernel(
    const float* __restrict__ x, const float* __restrict__ verts,
    const float* __restrict__ vnorm, const int* __restrict__ faces,
    float* __restrict__ tri, float* __restrict__ ncw,
    float* __restrict__ v1w, float* __restrict__ dfbw,
    int N, int V, int F) {
#pragma clang fp contract(off)
    int p = blockIdx.x;
    int tid = threadIdx.x;
    int wave = tid >> 6;
    int lane = tid & 63;
    if (p >= N) return;

    int gt = p * 256 + tid;
    if (gt < F) {
        int f0 = faces[gt * 3 + 0];
        int f1 = faces[gt * 3 + 1];
        int f2 = faces[gt * 3 + 2];
        float t0x = verts[f0 * 3 + 0], t0y = verts[f0 * 3 + 1], t0z = verts[f0 * 3 + 2];
        float ax = verts[f1 * 3 + 0], ay = verts[f1 * 3 + 1], az = verts[f1 * 3 + 2];
        float bx = verts[f2 * 3 + 0], by = verts[f2 * 3 + 1], bz = verts[f2 * 3 + 2];
        float4* t4 = (float4*)(tri + (size_t)gt * 12);
        t4[0] = make_float4(t0x, t0y, t0z, ax - t0x);
        t4[1] = make_float4(ay - t0y, az - t0z, bx - t0x, by - t0y);
        t4[2] = make_float4(bz - t0z, 0.f, 0.f, 0.f);
    }

    float xx = x[p * 3 + 0];
    float xy = x[p * 3 + 1];
    float xz = x[p * 3 + 2];

    unsigned long long ka[8], kb[8];
#pragma unroll
    for (int i = 0; i < 8; ++i) { ka[i] = ~0ULL; kb[i] = ~0ULL; }

    for (int va = tid; va < V; va += 512) {
        int vb = va + 256;
        bool hasB = vb < V;

        float avx = verts[va * 3 + 0];
        float avy = verts[va * 3 + 1];
        float avz = verts[va * 3 + 2];
        float bvx = 0.f, bvy = 0.f, bvz = 0.f;
        if (hasB) {
            bvx = verts[vb * 3 + 0];
            bvy = verts[vb * 3 + 1];
            bvz = verts[vb * 3 + 2];
        }

        float dxa = xx - avx, dya = xy - avy, dza = xz - avz;
        float d2a = ((dxa * dxa) + (dya * dya)) + (dza * dza);
        unsigned long long kA =
            (((unsigned long long)__float_as_uint(d2a)) << 32) | (unsigned int)va;
        if (kA < ka[7]) {
            ka[7] = kA;
#pragma unroll
            for (int j = 7; j > 0; --j) {
                if (ka[j] < ka[j - 1]) {
                    unsigned long long t = ka[j];
                    ka[j] = ka[j - 1];
                    ka[j - 1] = t;
                }
            }
        }

        if (hasB) {
            float dxb = xx - bvx, dyb = xy - bvy, dzb = xz - bvz;
            float d2b = ((dxb * dxb) + (dyb * dyb)) + (dzb * dzb);
            unsigned long long kB =
                (((unsigned long long)__float_as_uint(d2b)) << 32) | (unsigned int)vb;
            if (kB < kb[7]) {
                kb[7] = kB;
#pragma unroll
                for (int j = 7; j > 0; --j) {
                    if (kb[j] < kb[j - 1]) {
                        unsigned long long t = kb[j];
                        kb[j] = kb[j - 1];
                        kb[j - 1] = t;
                    }
                }
            }
        }
    }

    unsigned long long wsel[8];
#pragma unroll
    for (int j = 0; j < 8; ++j) {
        unsigned long long c = (ka[0] < kb[0]) ? ka[0] : kb[0];
        unsigned long long m = c;
#pragma unroll
        for (int s = 1; s < 64; s <<= 1) {
            unsigned long long o = __shfl_xor(m, s, 64);
            if (o < m) m = o;
        }
        if (c == m) {
            if (ka[0] == m) {
#pragma unroll
                for (int t = 0; t < 7; ++t) ka[t] = ka[t + 1];
                ka[7] = ~0ULL;
            } else {
#pragma unroll
                for (int t = 0; t < 7; ++t) kb[t] = kb[t + 1];
                kb[7] = ~0ULL;
            }
        }
        wsel[j] = m;
    }

    __shared__ unsigned long long cand[32];
    if (lane == 0) {
#pragma unroll
        for (int j = 0; j < 8; ++j) cand[wave * 8 + j] = wsel[j];
    }
    __syncthreads();
    if (wave != 0) return;

    unsigned long long c0 = (lane < 32) ? cand[lane] : ~0ULL;
    unsigned long long sel[8];
#pragma unroll
    for (int j = 0; j < 8; ++j) {
        unsigned long long m = c0;
#pragma unroll
        for (int s = 1; s < 64; s <<= 1) {
            unsigned long long o = __shfl_xor(m, s, 64);
            if (o < m) m = o;
        }
        if (c0 == m) c0 = ~0ULL;
        sel[j] = m;
    }

    if (lane != 0) return;

    float invk[8];
    float nsx = 0.f, nsy = 0.f, nsz = 0.f;
#pragma unroll
    for (int j = 0; j < 8; ++j) {
        int id = (int)(sel[j] & 0xffffffffu);
        float d2 = __uint_as_float((unsigned int)(sel[j] >> 32));
        float inv = 1.0f / fmaxf(d2, EPSF);
        invk[j] = inv;
        nsx = nsx + vnorm[id * 3 + 0] * inv;
        nsy = nsy + vnorm[id * 3 + 1] * inv;
        nsz = nsz + vnorm[id * 3 + 2] * inv;
    }
    float Wsum = ((invk[0] + invk[1]) + (invk[2] + invk[3])) +
                 ((invk[4] + invk[5]) + (invk[6] + invk[7]));

    int id0 = (int)(sel[0] & 0xffffffffu);
    float v1x = verts[id0 * 3 + 0];
    float v1y = verts[id0 * 3 + 1];
    float v1z = verts[id0 * 3 + 2];

    float dxv = xx - v1x, dyv = xy - v1y, dzv = xz - v1z;
    float d2v1 = fmaxf(((dxv * dxv) + (dyv * dyv)) + (dzv * dzv), EPSF);
    float den = 0.01f * d2v1;
    float tdx = dxv / den, tdy = dyv / den, tdz = dzv / den;

    float W = Wsum + 100.0f;
    float ntx = (nsx + tdx) / W;
    float nty = (nsy + tdy) / W;
    float ntz = (nsz + tdz) / W;
    float nrm = sqrtf(((ntx * ntx) + (nty * nty)) + (ntz * ntz)) + 1e-8f;
    float ncx = ntx / nrm, ncy = nty / nrm, ncz = ntz / nrm;

    float fx = v1x - xx, fy = v1y - xy, fz = v1z - xz;
    float fn = sqrtf(((fx * fx) + (fy * fy)) + (fz * fz)) + 1e-8f;
    fx = fx / fn; fy = fy / fn; fz = fz / fn;

    ncw[p * 3 + 0] = ncx; ncw[p * 3 + 1] = ncy; ncw[p * 3 + 2] = ncz;
    v1w[p * 3 + 0] = v1x; v1w[p * 3 + 1] = v1y; v1w[p * 3 + 2] = v1z;
    dfbw[p * 3 + 0] = fx; dfbw[p * 3 + 1] = fy; dfbw[p * 3 + 2] = fz;
}

// ---------------------------------------------------------------------------
// One MT test, R30-verbatim op order, contract off inside (R34-certified).
// ---------------------------------------------------------------------------
__device__ __forceinline__ float mt_test(
    float ox, float oy, float oz, float dx, float dy, float dz,
    const float4 A, const float4 B, const float4 C, float tb) {
#pragma clang fp contract(off)
    const float M = 1e-5f;  // graze margin (R21-certified)
    float e1x = A.w, e1y = B.x, e1z = B.y;
    float e2x = B.z, e2y = B.w, e2z = C.x;
    float tvx = ox - A.x;
    float tvy = oy - A.y;
    float tvz = oz - A.z;
    float qx = (tvy * e1z) - (tvz * e1y);
    float qy = (tvz * e1x) - (tvx * e1z);
    float qz = (tvx * e1y) - (tvy * e1x);
    float tq = ((e2x * qx) + (e2y * qy)) + (e2z * qz);
    float px = (dy * e2z) - (dz * e2y);
    float py = (dz * e2x) - (dx * e2z);
    float pz = (dx * e2y) - (dy * e2x);
    float det = ((e1x * px) + (e1y * py)) + (e1z * pz);
    bool ok = fabsf(det) > EPSF;
    float inv = ok ? (1.0f / det) : 0.0f;
    float u = (((tvx * px) + (tvy * py)) + (tvz * pz)) * inv;
    float v = (((dx * qx) + (dy * qy)) + (dz * qz)) * inv;
    float t = tq * inv;
    bool valid = ok && (u >= -M) && (v >= -M) && ((u + v) <= 1.0f + M) && (t > EPSF);
    return (valid && t < tb) ? t : tb;
}

// ---------------------------------------------------------------------------
// ray + reduce + finalize: 512 threads, block = 2 points {2b, 2b+1}.
// Each thread loads a triangle once (3x float4) and tests both points'
// primary rays. Pass-B per-point-guarded (block-uniform). Exact bitwise-min.
// ---------------------------------------------------------------------------
__global__ void __launch_bounds__(512) ray_fin_kernel(
    const float* __restrict__ x, const float* __restrict__ tri,
    const float* __restrict__ ncw, const float* __restrict__ v1w,
    const float* __restrict__ dfbw, float* __restrict__ out, int N, int F) {
#pragma clang fp contract(off)
    __shared__ unsigned int redA[8], redB[8];
    __shared__ unsigned int u1As, u1Bs, u2As, u2Bs, hAf, hBf;
    int b = blockIdx.x;
    int tid = threadIdx.x;
    int wave = tid >> 6;
    int lane = tid & 63;
    int pA = 2 * b;
    if (pA >= N) return;
    int pB = pA + 1;
    bool hasB = pB < N;      // uniform
    int pBs = hasB ? pB : pA;

    float axx = x[pA * 3 + 0], axy = x[pA * 3 + 1], axz = x[pA * 3 + 2];
    float Ancx = ncw[pA * 3 + 0], Ancy = ncw[pA * 3 + 1], Ancz = ncw[pA * 3 + 2];
    float Adbx = dfbw[pA * 3 + 0], Adby = dfbw[pA * 3 + 1], Adbz = dfbw[pA * 3 + 2];
    float Adax = -Ancx, Aday = -Ancy, Adaz = -Ancz;

    float bxx = x[pBs * 3 + 0], bxy = x[pBs * 3 + 1], bxz = x[pBs * 3 + 2];
    float Bncx = ncw[pBs * 3 + 0], Bncy = ncw[pBs * 3 + 1], Bncz = ncw[pBs * 3 + 2];
    float Bdbx = dfbw[pBs * 3 + 0], Bdby = dfbw[pBs * 3 + 1], Bdbz = dfbw[pBs * 3 + 2];
    float Bdax = -Bncx, Bday = -Bncy, Bdaz = -Bncz;

    const float INF = __uint_as_float(0x7f800000u);

    // -------- pass A: both points' primary rays (-nc), tri loaded once ----
    float tA = INF, tB = INF;
    for (int fi = tid; fi < F; fi += 512) {
        const float4 A4 = *(const float4*)(tri + (size_t)fi * 12);
        const float4 B4 = *(const float4*)(tri + (size_t)fi * 12 + 4);
        const float4 C4 = *(const float4*)(tri + (size_t)fi * 12 + 8);
        tA = mt_test(axx, axy, axz, Adax, Aday, Adaz, A4, B4, C4, tA);
        tB = mt_test(bxx, bxy, bxz, Bdax, Bday, Bdaz, A4, B4, C4, tB);
    }

    {
        unsigned int ma = __float_as_uint(tA);
        unsigned int mb = __float_as_uint(tB);
#pragma unroll
        for (int s = 1; s < 64; s <<= 1) {
            unsigned int oa = __shfl_xor(ma, s, 64);
            if (oa < ma) ma = oa;
            unsigned int ob = __shfl_xor(mb, s, 64);
            if (ob < mb) mb = ob;
        }
        if (lane == 0) { redA[wave] = ma; redB[wave] = mb; }
    }
    __syncthreads();
    if (tid == 0) {
        unsigned int u1A = min(min(min(redA[0], redA[1]), min(redA[2], redA[3])),
                               min(min(redA[4], redA[5]), min(redA[6], redA[7])));
        unsigned int u1B = min(min(min(redB[0], redB[1]), min(redB[2], redB[3])),
                               min(min(redB[4], redB[5]), min(redB[6], redB[7])));
        u1As = u1A; u1Bs = u1B;
        hAf = (u1A < 0x7f800000u) ? 1u : 0u;
        hBf = (u1B < 0x7f800000u) ? 1u : 0u;
    }
    __syncthreads();

    // -------- pass B: fallback rays (dfb), per-point-guarded --------------
    bool needA = (hAf == 0u);                 // block-uniform
    bool needB = hasB && (hBf == 0u);         // block-uniform
    if (needA || needB) {
        float sA = INF, sB = INF;
        for (int fi = tid; fi < F; fi += 512) {
            const float4 A4 = *(const float4*)(tri + (size_t)fi * 12);
            const float4 B4 = *(const float4*)(tri + (size_t)fi * 12 + 4);
            const float4 C4 = *(const float4*)(tri + (size_t)fi * 12 + 8);
            if (needA) sA = mt_test(axx, axy, axz, Adbx, Adby, Adbz, A4, B4, C4, sA);
            if (needB) sB = mt_test(bxx, bxy, bxz, Bdbx, Bdby, Bdbz, A4, B4, C4, sB);
        }
        unsigned int ma = __float_as_uint(sA);
        unsigned int mb = __float_as_uint(sB);
#pragma unroll
        for (int s = 1; s < 64; s <<= 1) {
            unsigned int oa = __shfl_xor(ma, s, 64);
            if (oa < ma) ma = oa;
            unsigned int ob = __shfl_xor(mb, s, 64);
            if (ob < mb) mb = ob;
        }
        if (lane == 0) { redA[wave] = ma; redB[wave] = mb; }
        __syncthreads();
        if (tid == 0) {
            u2As = min(min(min(redA[0], redA[1]), min(redA[2], redA[3])),
                       min(min(redA[4], redA[5]), min(redA[6], redA[7])));
            u2Bs = min(min(min(redB[0], redB[1]), min(redB[2], redB[3])),
                       min(min(redB[4], redB[5]), min(redB[6], redB[7])));
        }
    }

    // -------- finalize (verbatim per point), thread 0 ---------------------
    if (tid != 0) return;
    {
        float t1 = __uint_as_float(u1As);
        bool h1 = t1 < INF;
        float t2 = h1 ? INF : __uint_as_float(u2As);
        bool h2 = t2 < INF;
        float xcx, xcy, xcz;
        if (h1) {
            xcx = axx + ((-Ancx) * t1);
            xcy = axy + ((-Ancy) * t1);
            xcz = axz + ((-Ancz) * t1);
        } else if (h2) {
            xcx = axx + (Adbx * t2);
            xcy = axy + (Adby * t2);
            xcz = axz + (Adbz * t2);
        } else {
            xcx = v1w[pA * 3 + 0]; xcy = v1w[pA * 3 + 1]; xcz = v1w[pA * 3 + 2];
        }
        float s = (((axx - xcx) * Ancx) + ((axy - xcy) * Ancy)) + ((axz - xcz) * Ancz);
        out[pA * 3 + 0] = xcx;
        out[pA * 3 + 1] = xcy;
        out[pA * 3 + 2] = xcz;
        out[3 * N + pA] = s;
        out[4 * N + pA * 3 + 0] = Ancx;
        out[4 * N + pA * 3 + 1] = Ancy;
        out[4 * N + pA * 3 + 2] = Ancz;
    }
    if (hasB) {
        float t1 = __uint_as_float(u1Bs);
        bool h1 = t1 < INF;
        float t2 = h1 ? INF : __uint_as_float(u2Bs);
        bool h2 = t2 < INF;
        float xcx, xcy, xcz;
        if (h1) {
            xcx = bxx + ((-Bncx) * t1);
            xcy = bxy + ((-Bncy) * t1);
            xcz = bxz + ((-Bncz) * t1);
        } else if (h2) {
            xcx = bxx + (Bdbx * t2);
            xcy = bxy + (Bdby * t2);
            xcz = bxz + (Bdbz * t2);
        } else {
            xcx = v1w[pB * 3 + 0]; xcy = v1w[pB * 3 + 1]; xcz = v1w[pB * 3 + 2];
        }
        float s = (((bxx - xcx) * Bncx) + ((bxy - xcy) * Bncy)) + ((bxz - xcz) * Bncz);
        out[pB * 3 + 0] = xcx;
        out[pB * 3 + 1] = xcy;
        out[pB * 3 + 2] = xcz;
        out[3 * N + pB] = s;
        out[4 * N + pB * 3 + 0] = Bncx;
        out[4 * N + pB * 3 + 1] = Bncy;
        out[4 * N + pB * 3 + 2] = Bncz;
    }
}

// ---------------------------------------------------------------------------
extern "C" void kernel_launch(void* const* d_in, const int* in_sizes, int n_in,
                              void* d_out, int out_size, void* d_ws, size_t ws_size,
                              hipStream_t stream) {
    const float* x     = (const float*)d_in[0];
    const float* verts = (const float*)d_in[1];
    const float* vnorm = (const float*)d_in[2];
    const int*   faces = (const int*)d_in[3];
    int N = in_sizes[0] / 3;
    int V = in_sizes[1] / 3;
    int F = in_sizes[3] / 3;

    float* tri  = (float*)d_ws;          // F*12 floats (16B-aligned AoS)
    float* ncw  = tri + (size_t)F * 12;  // 3*N
    float* v1w  = ncw + 3 * N;           // 3*N
    float* dfbw = v1w + 3 * N;           // 3*N

    hipLaunchKernelGGL(knn_prep_kernel, dim3(N), dim3(256), 0, stream,
                       x, verts, vnorm, faces, tri, ncw, v1w, dfbw, N, V, F);
    int rblocks = (N + 1) / 2;
    hipLaunchKernelGGL(ray_fin_kernel, dim3(rblocks), dim3(512), 0, stream,
                       x, tri, ncw, v1w, dfbw, (float*)d_out, N, F);
}